// Round 4
// baseline (514.043 us; speedup 1.0000x reference)
//
#include <hip/hip_runtime.h>

#define HID 1024
#define SEQ 2048
#define NB  16

typedef __attribute__((ext_vector_type(8))) short bf16x8;
typedef __attribute__((ext_vector_type(4))) float f32x4;

static __device__ __forceinline__ short f2bf(float f) {
    union { float f; unsigned u; } v; v.f = f;
    unsigned u = v.u + 0x7fffu + ((v.u >> 16) & 1u);   // round-to-nearest-even
    return (short)(u >> 16);
}
static __device__ __forceinline__ unsigned pk2(float a, float b) {
    return (unsigned)(unsigned short)f2bf(a) | ((unsigned)(unsigned short)f2bf(b) << 16);
}
// async global->LDS, 16B per lane. LDS dest = wave-uniform base + lane*16.
static __device__ __forceinline__ void glds16(const void* g, void* l) {
    __builtin_amdgcn_global_load_lds(
        (const __attribute__((address_space(1))) unsigned*)g,
        (__attribute__((address_space(3))) unsigned*)l, 16, 0, 0);
}

// ---- fused prep, 3-dispatch plan. Sections (small latency-bound ones first so
// they overlap the BW-bound conversion):
//   [0,4)     qproj (non-atomic: one block owns a 256-n strip, all f)
//   [4,36)    zero scores
//   [36,52)   zero out_ctx
//   [52,1076) w1t transpose
//   [1076,+nconv) keys fp32->bf16
__global__ __launch_bounds__(256) void prep_all(const float* __restrict__ keys,
                                                short* __restrict__ kbf,
                                                const float* __restrict__ W1,
                                                const float* __restrict__ queries,
                                                const float* __restrict__ b1,
                                                short* __restrict__ w1t,
                                                float* __restrict__ qproj,
                                                float* __restrict__ scores,
                                                float* __restrict__ ctx,
                                                int nconv) {
    __shared__ float shmem[2048];          // 8 KB, aliased per section
    const int tid = threadIdx.x;
    int bw = blockIdx.x;

    if (bw < 4) {  // qproj[b][n] = b1[n] + sum_f q[b][f]*W1[f][n], n strip of 256
        const int n = bw * 256 + tid;
        float acc[16];
#pragma unroll
        for (int b = 0; b < 16; ++b) acc[b] = b1[n];
        for (int f0 = 0; f0 < HID; f0 += 128) {
#pragma unroll
            for (int j = 0; j < 8; ++j) {   // stage q[0:16][f0:f0+128] (8 KB)
                const int idx = tid * 8 + j;
                shmem[idx] = queries[(idx >> 7) * HID + f0 + (idx & 127)];
            }
            __syncthreads();
#pragma unroll 4
            for (int f = 0; f < 128; ++f) {
                const float w = W1[(size_t)(f0 + f) * HID + n];
#pragma unroll
                for (int b = 0; b < 16; ++b)
                    acc[b] += shmem[b * 128 + f] * w;
            }
            __syncthreads();
        }
#pragma unroll
        for (int b = 0; b < 16; ++b) qproj[b * HID + n] = acc[b];
        return;
    }
    bw -= 4;
    if (bw < 32) {  // zero scores
        float4 z = {0.f, 0.f, 0.f, 0.f};
        *(float4*)(scores + (size_t)(bw * 256 + tid) * 4) = z;
        return;
    }
    bw -= 32;
    if (bw < 16) {  // zero out_ctx
        float4 z = {0.f, 0.f, 0.f, 0.f};
        *(float4*)(ctx + (size_t)(bw * 256 + tid) * 4) = z;
        return;
    }
    bw -= 16;
    if (bw < 1024) {  // w1t[n][k] = bf16(W1[H+k][n])
        float (*t)[33] = (float(*)[33])shmem;   // 32x33 floats
        const int k0 = (bw & 31) * 32;
        const int n0 = (bw >> 5) * 32;
        const int tx = tid & 31, ty = tid >> 5;
#pragma unroll
        for (int i = 0; i < 32; i += 8)
            t[ty + i][tx] = W1[(size_t)(HID + k0 + ty + i) * HID + n0 + tx];
        __syncthreads();
#pragma unroll
        for (int i = 0; i < 32; i += 8)
            w1t[(size_t)(n0 + ty + i) * HID + k0 + tx] = f2bf(t[tx][ty + i]);
        return;
    }
    bw -= 1024;
    if (bw < nconv) {  // keys fp32 -> bf16, 8 elems/thread
        const size_t i = ((size_t)bw * 256 + tid) * 8;
        const float4 a = *(const float4*)(keys + i);
        const float4 b = *(const float4*)(keys + i + 4);
        int4 o;
        o.x = (int)pk2(a.x, a.y); o.y = (int)pk2(a.z, a.w);
        o.z = (int)pk2(b.x, b.y); o.w = (int)pk2(b.z, b.w);
        *(int4*)(kbf + i) = o;
    }
}

// ---- main fused score GEMM: 128x128 tile, BK=32, 4 waves (2x2), 4x4 frags/wave.
// XCD swizzle: the 8 n-blocks sharing one m-tile get linear ids {j, j+8, .., j+56}
// (same id mod 8 -> same XCD under round-robin dispatch, temporally adjacent), so
// the shared A-tile is fetched into ONE XCD's L2 instead of eight.
template<int PRE>
__global__ __launch_bounds__(256) void score_gemm128(const float* __restrict__ keys,
                                                     const short* __restrict__ kbf,
                                                     const short* __restrict__ w1t,
                                                     const float* __restrict__ qproj,
                                                     const float* __restrict__ W2,
                                                     float* __restrict__ scores) {
    __shared__ short As[128 * 32];  // [m][k] bf16, unpadded (glds layout)
    __shared__ short Bs[128 * 32];  // [n][k] bf16, unpadded

    const int tid  = threadIdx.x;
    const int lane = tid & 63;
    const int wave = tid >> 6;

    const int b     = blockIdx.x + blockIdx.y * 8;      // linear id, 0..2047
    const int n_idx = (b >> 3) & 7;
    const int m_idx = ((b >> 6) << 3) | (b & 7);
    const int n0 = n_idx * 128;
    const int m0 = m_idx * 128;
    const int batch = m_idx >> 4;                       // 16 m-tiles per batch

    const int wm = wave >> 1, wn = wave & 1;   // wave quadrant
    const int q = lane >> 4, c = lane & 15;

    // glds per-call lane mapping: row = callrow + lane/4, k-chunk = (lane&3)*8
    const int lrow = lane >> 2;
    const int lk   = (lane & 3) * 8;

    f32x4 acc[4][4] = {};

    for (int k0 = 0; k0 < HID; k0 += 32) {
        // B: 8 KB via 2 glds calls per wave
#pragma unroll
        for (int call = 0; call < 2; ++call) {
            const int rbase = (wave * 2 + call) * 16;
            glds16(w1t + (size_t)(n0 + rbase + lrow) * HID + k0 + lk,
                   &Bs[rbase * 32]);
        }
        if (PRE) {
#pragma unroll
            for (int call = 0; call < 2; ++call) {
                const int rbase = (wave * 2 + call) * 16;
                glds16(kbf + (size_t)(m0 + rbase + lrow) * HID + k0 + lk,
                       &As[rbase * 32]);
            }
        } else {
            // A: convert fp32->bf16 in-register. thread t: row t>>1, half t&1
            const int r = tid >> 1, h = (tid & 1) * 16;
            const float* src = keys + (size_t)(m0 + r) * HID + k0 + h;
            const float4 v0 = *(const float4*)(src + 0);
            const float4 v1 = *(const float4*)(src + 4);
            const float4 v2 = *(const float4*)(src + 8);
            const float4 v3 = *(const float4*)(src + 12);
            int4 o0, o1;
            o0.x = (int)pk2(v0.x, v0.y); o0.y = (int)pk2(v0.z, v0.w);
            o0.z = (int)pk2(v1.x, v1.y); o0.w = (int)pk2(v1.z, v1.w);
            o1.x = (int)pk2(v2.x, v2.y); o1.y = (int)pk2(v2.z, v2.w);
            o1.z = (int)pk2(v3.x, v3.y); o1.w = (int)pk2(v3.z, v3.w);
            *(int4*)&As[r * 32 + h + 0] = o0;
            *(int4*)&As[r * 32 + h + 8] = o1;
        }
        __syncthreads();

        bf16x8 af[4], bf[4];
#pragma unroll
        for (int i = 0; i < 4; ++i)
            af[i] = *(const bf16x8*)&As[(wm * 64 + i * 16 + c) * 32 + q * 8];
#pragma unroll
        for (int i = 0; i < 4; ++i)
            bf[i] = *(const bf16x8*)&Bs[(wn * 64 + i * 16 + c) * 32 + q * 8];
#pragma unroll
        for (int mi = 0; mi < 4; ++mi)
#pragma unroll
            for (int ni = 0; ni < 4; ++ni)
                acc[mi][ni] = __builtin_amdgcn_mfma_f32_16x16x32_bf16(af[mi], bf[ni], acc[mi][ni], 0, 0, 0);
        __syncthreads();
    }

    // epilogue: relu(acc + qproj) * W2, reduce over this wave's 64 n-cols
    const float* qp = qproj + batch * HID + n0 + wn * 64;
    const float* w2 = W2 + n0 + wn * 64;
    float psum[4][4] = {};
#pragma unroll
    for (int ni = 0; ni < 4; ++ni) {
        const float qv = qp[ni * 16 + c];
        const float wv = w2[ni * 16 + c];
#pragma unroll
        for (int mi = 0; mi < 4; ++mi)
#pragma unroll
            for (int r = 0; r < 4; ++r)
                psum[mi][r] += fmaxf(acc[mi][ni][r] + qv, 0.f) * wv;
    }
#pragma unroll
    for (int m = 1; m < 16; m <<= 1)
#pragma unroll
        for (int mi = 0; mi < 4; ++mi)
#pragma unroll
            for (int r = 0; r < 4; ++r)
                psum[mi][r] += __shfl_xor(psum[mi][r], m, 64);
    if (c == 0) {
#pragma unroll
        for (int mi = 0; mi < 4; ++mi) {
            const int row = m0 + wm * 64 + mi * 16 + q * 4;
#pragma unroll
            for (int r = 0; r < 4; ++r)
                atomicAdd(&scores[row + r], psum[mi][r]);
        }
    }
}

// ---- fused softmax + context. Each block redundantly computes the batch softmax
// from scores (2048 floats — cheap); block x==32 writes alphas, blocks x<32 each
// accumulate a 64-row slice of context (ctx pre-zeroed in prep).
__global__ __launch_bounds__(256) void softmax_context(const float* __restrict__ scores,
                                                       const float* __restrict__ values,
                                                       float* __restrict__ alphas,
                                                       float* __restrict__ ctx) {
    __shared__ float red[256];
    __shared__ float ash[SEQ];
    const int b = blockIdx.y;
    const int x = blockIdx.x;
    const int tid = threadIdx.x;

    float loc[8];
    float mx = -1e30f;
#pragma unroll
    for (int i = 0; i < 8; ++i) {
        loc[i] = scores[b * SEQ + tid + i * 256];
        mx = fmaxf(mx, loc[i]);
    }
    red[tid] = mx; __syncthreads();
    for (int s = 128; s > 0; s >>= 1) {
        if (tid < s) red[tid] = fmaxf(red[tid], red[tid + s]);
        __syncthreads();
    }
    mx = red[0]; __syncthreads();
    float sum = 0.f;
#pragma unroll
    for (int i = 0; i < 8; ++i) { loc[i] = expf(loc[i] - mx); sum += loc[i]; }
    red[tid] = sum; __syncthreads();
    for (int s = 128; s > 0; s >>= 1) {
        if (tid < s) red[tid] += red[tid + s];
        __syncthreads();
    }
    const float inv = 1.0f / red[0];
#pragma unroll
    for (int i = 0; i < 8; ++i) ash[tid + i * 256] = loc[i] * inv;
    __syncthreads();

    if (x == 32) {  // alpha writer
#pragma unroll
        for (int i = 0; i < 8; ++i)
            alphas[b * SEQ + tid + i * 256] = loc[i] * inv;
        return;
    }
    // context slice: rows [x*64, x*64+64)
    const int s0 = x * 64;
    const int col = tid * 4;
    float4 acc4 = {0.f, 0.f, 0.f, 0.f};
    for (int i = 0; i < 64; ++i) {
        const float a = ash[s0 + i];
        const float4 v = *(const float4*)(values + (size_t)(b * SEQ + s0 + i) * HID + col);
        acc4.x += a * v.x; acc4.y += a * v.y; acc4.z += a * v.z; acc4.w += a * v.w;
    }
    float* cp = ctx + b * HID + col;
    atomicAdd(cp + 0, acc4.x);
    atomicAdd(cp + 1, acc4.y);
    atomicAdd(cp + 2, acc4.z);
    atomicAdd(cp + 3, acc4.w);
}

extern "C" void kernel_launch(void* const* d_in, const int* in_sizes, int n_in,
                              void* d_out, int out_size, void* d_ws, size_t ws_size,
                              hipStream_t stream) {
    const float* queries = (const float*)d_in[0];
    const float* keys    = (const float*)d_in[1];
    const float* values  = (const float*)d_in[2];
    const float* W1      = (const float*)d_in[3];
    const float* b1      = (const float*)d_in[4];
    const float* W2      = (const float*)d_in[5];
    // d_in[6] = b2: softmax is shift-invariant; b2 affects neither alphas nor context.

    float* out_ctx   = (float*)d_out;            // [16,1024]
    float* out_alpha = (float*)d_out + NB * HID; // [16,2048]

    char* ws = (char*)d_ws;
    float* scores = (float*)ws;                       // 131072 B
    float* qproj  = (float*)(ws + 131072);            // 65536 B
    short* w1t    = (short*)(ws + 196608);            // 2 MiB
    short* kbf    = (short*)(ws + 2293760);           // 64 MiB (preconv path)

    const size_t need_pre = 2293760ull + 67108864ull;
    const bool pre = ws_size >= need_pre;
    const int nconv = pre ? 16384 : 0;   // 33.5M elems / 2048 per block

    prep_all<<<4 + 32 + 16 + 1024 + nconv, 256, 0, stream>>>(
        keys, kbf, W1, queries, b1, w1t, qproj, scores, out_ctx, nconv);

    if (pre)
        score_gemm128<1><<<dim3(8, 256), 256, 0, stream>>>(keys, kbf, w1t, qproj, W2, scores);
    else
        score_gemm128<0><<<dim3(8, 256), 256, 0, stream>>>(keys, kbf, w1t, qproj, W2, scores);

    softmax_context<<<dim3(33, NB), 256, 0, stream>>>(scores, values, out_alpha, out_ctx);
}